// Round 14
// baseline (105.145 us; speedup 1.0000x reference)
//
#include <hip/hip_runtime.h>
#include <hip/hip_bf16.h>

// NonLocalBlock fp32 -> reduced split-bf16 MFMA, MI355X.
// Error budget (validated r8/r9): check on z attenuates y-errors ~0.11x and
// softmax errors average ~1/80; dropped p_lo/e_lo/g_lo keep absmax at 7.6e-6.
// r14: (1) transpose_g folded into conv3 (correct M-view mapping this time:
// value at (o,s) has m = o*200+(s>>5), c = s&31; dest Gt[c][(m&~31)+inv_sigma
// (m&31)]). (2) attn k-loop fully unrolled -> compiler schedules loads 2-3
// iters deep within the 170-reg (256,3) cap.
#define BATCH 2
#define CIN   64
#define COUT  32
#define HW    6400
#define PB    (COUT*HW)      // 204800 elems per batch (M-view 6400x32)
#define XB    (CIN*HW)
#define KSPLIT 5             // keys/split = 1280 = 10 iters x 128
#define LOG2E 1.4426950408889634f

typedef __attribute__((ext_vector_type(8))) short  bf16x8;
typedef __attribute__((ext_vector_type(4))) float  f32x4;

typedef unsigned short ushort;
typedef unsigned int   uint;

__device__ inline uint pk2(float a, float b) {
  __hip_bfloat162 h = __float22bfloat162_rn(make_float2(a, b));
  union { __hip_bfloat162 h2; uint u; } cv; cv.h2 = h;
  return cv.u;
}
__device__ inline float up_lo(uint u) { return __uint_as_float(u << 16); }

#define MFMA16(a, bop, c) __builtin_amdgcn_mfma_f32_16x16x32_bf16((a), (bop), (c), 0, 0, 0)

// ---------------------------------------------------------------------------
// Kernel 1: three 1x1 convs -> bf16 buffers.
// theta (which=0): scaled by LOG2E, hi+lo split -> T_hi/T_lo (flat [o][s]).
// phi (which=1): hi only -> P_hi (flat [o][s]).
// g (which=2): hi only, written DIRECTLY as the sigma-permuted transpose:
//   value at (o,s) is G_M[m][c] with m = o*200 + (s>>5), c = s&31;
//   dest = Gt[c][ (m&~31) + 16*((m>>3)&1) + 8*((m>>2)&1) + 4*((m>>4)&1)
//                + (m&3) ]   (= inv_sigma; attn reads G_M[sigma(n'&31)..][c])
// grid (50, 6, B) x 128.
// ---------------------------------------------------------------------------
__global__ __launch_bounds__(128) void conv3_kernel(
    const float* __restrict__ x,
    const float* __restrict__ w0, const float* __restrict__ bb0,   // theta
    const float* __restrict__ w1, const float* __restrict__ bb1,   // phi
    const float* __restrict__ w2, const float* __restrict__ bb2,   // g
    ushort* __restrict__ T_hi, ushort* __restrict__ T_lo,
    ushort* __restrict__ P_hi, ushort* __restrict__ Gt_hi) {
  const int which = blockIdx.y >> 1;
  const int oh    = blockIdx.y & 1;               // o-half: 16 channels
  const float* w  = (which == 0) ? w0 : (which == 1) ? w1 : w2;
  const float* bv = (which == 0) ? bb0 : (which == 1) ? bb1 : bb2;
  const int b = blockIdx.z;
  const int s = blockIdx.x * 128 + threadIdx.x;   // 50*128 == 6400

  __shared__ float wsm[16 * CIN];                 // 4 KiB (this half's rows)
  for (int i = threadIdx.x; i < 16 * CIN; i += 128)
    wsm[i] = w[oh * 16 * CIN + i];
  __syncthreads();

  float xr[CIN];
#pragma unroll
  for (int c = 0; c < CIN; ++c) xr[c] = x[b * XB + c * HW + s];   // coalesced

  for (int oi = 0; oi < 16; ++oi) {
    const int o = oh * 16 + oi;
    const float4* wr = (const float4*)&wsm[oi * CIN];
    float acc = 0.f;
#pragma unroll
    for (int q = 0; q < CIN / 4; ++q) {
      float4 wv = wr[q];
      acc += wv.x * xr[4*q] + wv.y * xr[4*q+1] + wv.z * xr[4*q+2] + wv.w * xr[4*q+3];
    }
    acc += bv[o];
    if (which == 0) acc *= LOG2E;                 // exp(S) == exp2(S*log2e)
    uint hb = pk2(acc, 0.f) & 0xFFFFu;
    if (which == 2) {
      const int m  = o * 200 + (s >> 5);          // M-view row of this value
      const int np = (m & ~31) + 16*((m>>3)&1) + 8*((m>>2)&1)
                   + 4*((m>>4)&1) + (m & 3);      // inv_sigma within /32
      Gt_hi[b * PB + (s & 31) * HW + np] = (ushort)hb;   // scattered 2B, L2-merged
    } else {
      const int f = b * PB + o * HW + s;
      if (which == 0) {
        T_hi[f] = (ushort)hb;
        float hf = up_lo(hb);
        T_lo[f] = (ushort)(pk2(acc - hf, 0.f) & 0xFFFFu);
      } else {
        P_hi[f] = (ushort)hb;
      }
    }
  }
}

// ---------------------------------------------------------------------------
// Kernel 2: fused attention, register-direct fragments, 64 q/block.
// grid (100 q-tiles, KSPLIT, B) x 256 (4 waves). Wave w owns key-slice w:
// keys ks*1280 + i*128 + w*32, i = 0..9 (FULLY UNROLLED -> compiler deep-
// pipelines the 4 global 16B loads per iter across iterations).
// Fragment sources per lane:
//   pa: P row kbase+l15,   chans g*8..   pb: +16 rows
//   g0: Gt chan row l15, perm-keys kbase+g*8..   g1: +16 chan rows
// Math (validated): S' = p_hi*(t'_hi+t'_lo); e = exp2(S'); Y += bf16(e)*g_hi.
// ---------------------------------------------------------------------------
__global__ __launch_bounds__(256, 3) void attn_kernel(
    const ushort* __restrict__ T_hi, const ushort* __restrict__ T_lo,
    const ushort* __restrict__ P_hi, const ushort* __restrict__ Gt_hi,
    float* __restrict__ Yp,   // [KSPLIT][B][HW][32]
    float* __restrict__ Dp) { // [KSPLIT][B][HW]
  const int b     = blockIdx.z;
  const int ks    = blockIdx.y;
  const int q_blk = blockIdx.x;          // 0..99, 64 queries each
  const int tid   = threadIdx.x;
  const int w     = tid >> 6;            // wave 0..3 = key slice
  const int lane  = tid & 63;
  const int l15   = lane & 15;
  const int g     = lane >> 4;

  __shared__ float yl[4 * 32 * 33 + 4 * 32];   // epilogue only (17.2 KB)

  const int kbase = ks * 1280 + w * 32;  // this wave's first key

  // T fragments (theta*log2e, split) for q-subtiles s2 = 0..3
  bf16x8 t_hi[4], t_lo[4];
#pragma unroll
  for (int s2 = 0; s2 < 4; ++s2) {
    const int qrow = q_blk * 64 + s2 * 16 + l15;
    t_hi[s2] = *(const bf16x8*)&T_hi[b * PB + qrow * 32 + g * 8];
    t_lo[s2] = *(const bf16x8*)&T_lo[b * PB + qrow * 32 + g * 8];
  }

  // per-lane fragment sources
  const ushort* pg = P_hi + b * PB + (kbase + l15) * 32 + g * 8;
  const ushort* gg = Gt_hi + b * PB + l15 * HW + kbase + g * 8;

  f32x4 acc0[4] = {{0,0,0,0},{0,0,0,0},{0,0,0,0},{0,0,0,0}};  // chans 0..15
  f32x4 acc1[4] = {{0,0,0,0},{0,0,0,0},{0,0,0,0},{0,0,0,0}};  // chans 16..31
  float denom[4] = {0.f, 0.f, 0.f, 0.f};

#pragma unroll
  for (int i = 0; i < 10; ++i) {
    const ushort* pgi = pg + i * 4096;           // +128 keys * 32 chans
    const ushort* ggi = gg + i * 128;            // +128 keys
    const bf16x8 pa = *(const bf16x8*)pgi;
    const bf16x8 pb = *(const bf16x8*)(pgi + 512);       // +16 key rows
    const bf16x8 g0 = *(const bf16x8*)ggi;
    const bf16x8 g1 = *(const bf16x8*)(ggi + 16 * HW);   // +16 chan rows

#pragma unroll
    for (int s2 = 0; s2 < 4; ++s2) {
      f32x4 sa = {0.f,0.f,0.f,0.f};
      f32x4 sb = {0.f,0.f,0.f,0.f};
      __builtin_amdgcn_s_setprio(1);
      sa = MFMA16(pa, t_hi[s2], sa);
      sa = MFMA16(pa, t_lo[s2], sa);
      sb = MFMA16(pb, t_hi[s2], sb);
      sb = MFMA16(pb, t_lo[s2], sb);
      __builtin_amdgcn_s_setprio(0);

      const float ea0 = __builtin_amdgcn_exp2f(sa[0]);
      const float ea1 = __builtin_amdgcn_exp2f(sa[1]);
      const float ea2 = __builtin_amdgcn_exp2f(sa[2]);
      const float ea3 = __builtin_amdgcn_exp2f(sa[3]);
      const float eb0 = __builtin_amdgcn_exp2f(sb[0]);
      const float eb1 = __builtin_amdgcn_exp2f(sb[1]);
      const float eb2 = __builtin_amdgcn_exp2f(sb[2]);
      const float eb3 = __builtin_amdgcn_exp2f(sb[3]);
      denom[s2] += ((ea0 + ea1) + (ea2 + ea3)) + ((eb0 + eb1) + (eb2 + eb3));

      union { uint u[4]; bf16x8 v; } ph;
      ph.u[0] = pk2(ea0, ea1); ph.u[1] = pk2(ea2, ea3);
      ph.u[2] = pk2(eb0, eb1); ph.u[3] = pk2(eb2, eb3);

      __builtin_amdgcn_s_setprio(1);
      acc0[s2] = MFMA16(ph.v, g0, acc0[s2]);
      acc1[s2] = MFMA16(ph.v, g1, acc1[s2]);
      __builtin_amdgcn_s_setprio(0);
    }
  }

  // epilogue: combine the 4 key-slice waves via LDS, two passes of 32 queries
  float* dl = yl + 4 * 32 * 33;
  const int c  = tid & 31;
  const int q0 = tid >> 5;               // 0..7

#pragma unroll
  for (int p = 0; p < 2; ++p) {
    __syncthreads();                     // all waves ready / yl reusable
#pragma unroll
    for (int sl = 0; sl < 2; ++sl) {
      const int s2 = p * 2 + sl;
      float dn = denom[s2];
      dn += __shfl_xor(dn, 16);
      dn += __shfl_xor(dn, 32);
#pragma unroll
      for (int r = 0; r < 4; ++r) {
        yl[(w * 32 + sl * 16 + 4 * g + r) * 33 + l15]      = acc0[s2][r];
        yl[(w * 32 + sl * 16 + 4 * g + r) * 33 + 16 + l15] = acc1[s2][r];
      }
      if (g == 0) dl[w * 32 + sl * 16 + l15] = dn;
    }
    __syncthreads();

#pragma unroll
    for (int rr = 0; rr < 4; ++rr) {
      const int row = rr * 8 + q0;       // 0..31 within this pass
      float y = 0.f, d = 0.f;
#pragma unroll
      for (int k2 = 0; k2 < 4; ++k2) {
        y += yl[(k2 * 32 + row) * 33 + c];
        d += dl[k2 * 32 + row];
      }
      const int qrow = q_blk * 64 + p * 32 + row;
      Yp[((size_t)(ks * BATCH + b)) * PB + qrow * 32 + c] = y;
      if (c == 0) Dp[((size_t)(ks * BATCH + b)) * HW + qrow] = d;
    }
  }
}

// ---------------------------------------------------------------------------
// Kernel 3: final 1x1 conv fused with KSPLIT combine + normalize.
// grid (50, 2, B) x 128.
// ---------------------------------------------------------------------------
__global__ __launch_bounds__(128) void conv_out_kernel(
    const float* __restrict__ Yp, const float* __restrict__ Dp,
    const float* __restrict__ wy, const float* __restrict__ by,
    float* __restrict__ z) {
  const int b  = blockIdx.z;
  const int ih = blockIdx.y;            // i-half: 32 channels
  const int s  = blockIdx.x * 128 + threadIdx.x;

  __shared__ float wsm[32 * COUT];      // 4 KiB (this half's rows)
  for (int i = threadIdx.x; i < 32 * COUT; i += 128)
    wsm[i] = wy[ih * 32 * COUT + i];
  __syncthreads();

  float yr[COUT];
#pragma unroll
  for (int o = 0; o < COUT; ++o) {
    const int f = o * HW + s;
    const int n = f >> 5;
    float y = 0.f, d = 0.f;
#pragma unroll
    for (int ksi = 0; ksi < KSPLIT; ++ksi) {
      y += Yp[((size_t)(ksi * BATCH + b)) * PB + f];
      d += Dp[((size_t)(ksi * BATCH + b)) * HW + n];
    }
    yr[o] = y / d;
  }

  for (int ii = 0; ii < 32; ++ii) {
    const int i = ih * 32 + ii;
    const float4* wr = (const float4*)&wsm[ii * COUT];
    float acc = 0.f;
#pragma unroll
    for (int q = 0; q < COUT / 4; ++q) {
      float4 wv = wr[q];
      acc += wv.x * yr[4*q] + wv.y * yr[4*q+1] + wv.z * yr[4*q+2] + wv.w * yr[4*q+3];
    }
    z[(size_t)b * XB + i * HW + s] = acc + by[i];
  }
}

// ---------------------------------------------------------------------------
extern "C" void kernel_launch(void* const* d_in, const int* in_sizes, int n_in,
                              void* d_out, int out_size, void* d_ws, size_t ws_size,
                              hipStream_t stream) {
  const float* x       = (const float*)d_in[0];
  const float* w_g     = (const float*)d_in[1];
  const float* b_g     = (const float*)d_in[2];
  const float* w_phi   = (const float*)d_in[3];
  const float* b_phi   = (const float*)d_in[4];
  const float* w_theta = (const float*)d_in[5];
  const float* b_theta = (const float*)d_in[6];
  const float* w_y     = (const float*)d_in[7];
  const float* b_y     = (const float*)d_in[8];
  float* z = (float*)d_out;

  char* base = (char*)d_ws;
  const size_t BF = (size_t)BATCH * PB * sizeof(ushort);  // 819200 B
  ushort* T_hi  = (ushort*)(base);
  ushort* T_lo  = (ushort*)(base + 1 * BF);
  ushort* P_hi  = (ushort*)(base + 2 * BF);
  ushort* Gt_hi = (ushort*)(base + 3 * BF);
  float*  Yp    = (float*)(base + 4 * BF);                 // KSPLIT*B*PB f32
  float*  Dp    = (float*)(base + 4 * BF +
                           (size_t)KSPLIT * BATCH * PB * sizeof(float));

  conv3_kernel<<<dim3(50, 6, BATCH), 128, 0, stream>>>(
      x, w_theta, b_theta, w_phi, b_phi, w_g, b_g,
      T_hi, T_lo, P_hi, Gt_hi);
  attn_kernel<<<dim3(100, KSPLIT, BATCH), 256, 0, stream>>>(
      T_hi, T_lo, P_hi, Gt_hi, Yp, Dp);
  conv_out_kernel<<<dim3(50, 2, BATCH), 128, 0, stream>>>(Yp, Dp, w_y, b_y, z);
}

// Round 15
// 57.127 us; speedup vs baseline: 1.8406x; 1.8406x over previous
//
#include <hip/hip_runtime.h>
#include <hip/hip_bf16.h>

// NonLocalBlock fp32 -> reduced split-bf16 MFMA, MI355X.
// Error budget (validated r8/r9): check on z attenuates y-errors ~0.11x and
// softmax errors average ~1/80; dropped p_lo/e_lo/g_lo keep absmax at 7.6e-6.
// r15: revert r14's full unroll (it spilled: VGPR=84 + 154MB scratch writes).
// Keep: r14's conv3-fused Gt transpose (validated), r13's rotating 2-deep
// register pipeline attn loop (measured best, no spill).
#define BATCH 2
#define CIN   64
#define COUT  32
#define HW    6400
#define PB    (COUT*HW)      // 204800 elems per batch (M-view 6400x32)
#define XB    (CIN*HW)
#define KSPLIT 5             // keys/split = 1280 = 10 iters x 128
#define LOG2E 1.4426950408889634f

typedef __attribute__((ext_vector_type(8))) short  bf16x8;
typedef __attribute__((ext_vector_type(4))) float  f32x4;

typedef unsigned short ushort;
typedef unsigned int   uint;

__device__ inline uint pk2(float a, float b) {
  __hip_bfloat162 h = __float22bfloat162_rn(make_float2(a, b));
  union { __hip_bfloat162 h2; uint u; } cv; cv.h2 = h;
  return cv.u;
}
__device__ inline float up_lo(uint u) { return __uint_as_float(u << 16); }

#define MFMA16(a, bop, c) __builtin_amdgcn_mfma_f32_16x16x32_bf16((a), (bop), (c), 0, 0, 0)

// ---------------------------------------------------------------------------
// Kernel 1: three 1x1 convs -> bf16 buffers.
// theta (which=0): scaled by LOG2E, hi+lo split -> T_hi/T_lo (flat [o][s]).
// phi (which=1): hi only -> P_hi (flat [o][s]).
// g (which=2): hi only, written DIRECTLY as the sigma-permuted transpose:
//   value at (o,s) is G_M[m][c] with m = o*200 + (s>>5), c = s&31;
//   dest = Gt[c][ (m&~31) + 16*((m>>3)&1) + 8*((m>>2)&1) + 4*((m>>4)&1)
//                + (m&3) ]   (= inv_sigma; attn reads G_M[sigma(n'&31)..][c])
// grid (50, 6, B) x 128.  [validated r14]
// ---------------------------------------------------------------------------
__global__ __launch_bounds__(128) void conv3_kernel(
    const float* __restrict__ x,
    const float* __restrict__ w0, const float* __restrict__ bb0,   // theta
    const float* __restrict__ w1, const float* __restrict__ bb1,   // phi
    const float* __restrict__ w2, const float* __restrict__ bb2,   // g
    ushort* __restrict__ T_hi, ushort* __restrict__ T_lo,
    ushort* __restrict__ P_hi, ushort* __restrict__ Gt_hi) {
  const int which = blockIdx.y >> 1;
  const int oh    = blockIdx.y & 1;               // o-half: 16 channels
  const float* w  = (which == 0) ? w0 : (which == 1) ? w1 : w2;
  const float* bv = (which == 0) ? bb0 : (which == 1) ? bb1 : bb2;
  const int b = blockIdx.z;
  const int s = blockIdx.x * 128 + threadIdx.x;   // 50*128 == 6400

  __shared__ float wsm[16 * CIN];                 // 4 KiB (this half's rows)
  for (int i = threadIdx.x; i < 16 * CIN; i += 128)
    wsm[i] = w[oh * 16 * CIN + i];
  __syncthreads();

  float xr[CIN];
#pragma unroll
  for (int c = 0; c < CIN; ++c) xr[c] = x[b * XB + c * HW + s];   // coalesced

  for (int oi = 0; oi < 16; ++oi) {
    const int o = oh * 16 + oi;
    const float4* wr = (const float4*)&wsm[oi * CIN];
    float acc = 0.f;
#pragma unroll
    for (int q = 0; q < CIN / 4; ++q) {
      float4 wv = wr[q];
      acc += wv.x * xr[4*q] + wv.y * xr[4*q+1] + wv.z * xr[4*q+2] + wv.w * xr[4*q+3];
    }
    acc += bv[o];
    if (which == 0) acc *= LOG2E;                 // exp(S) == exp2(S*log2e)
    uint hb = pk2(acc, 0.f) & 0xFFFFu;
    if (which == 2) {
      const int m  = o * 200 + (s >> 5);          // M-view row of this value
      const int np = (m & ~31) + 16*((m>>3)&1) + 8*((m>>2)&1)
                   + 4*((m>>4)&1) + (m & 3);      // inv_sigma within /32
      Gt_hi[b * PB + (s & 31) * HW + np] = (ushort)hb;   // scattered 2B, L2-merged
    } else {
      const int f = b * PB + o * HW + s;
      if (which == 0) {
        T_hi[f] = (ushort)hb;
        float hf = up_lo(hb);
        T_lo[f] = (ushort)(pk2(acc - hf, 0.f) & 0xFFFFu);
      } else {
        P_hi[f] = (ushort)hb;
      }
    }
  }
}

// ---------------------------------------------------------------------------
// Kernel 2: fused attention, register-direct fragments, 64 q/block.
// grid (100 q-tiles, KSPLIT, B) x 256 (4 waves). Wave w owns key-slice w:
// keys ks*1280 + i*128 + w*32, i = 0..9 (runtime loop, rotating 2-deep
// register double-buffer -- r14's full unroll spilled, this doesn't).
// Fragment sources per lane:
//   pa: P row kbase+l15,   chans g*8..   pb: +16 rows
//   g0: Gt chan row l15, perm-keys kbase+g*8..   g1: +16 chan rows
// Math (validated): S' = p_hi*(t'_hi+t'_lo); e = exp2(S'); Y += bf16(e)*g_hi.
// ---------------------------------------------------------------------------
__global__ __launch_bounds__(256, 3) void attn_kernel(
    const ushort* __restrict__ T_hi, const ushort* __restrict__ T_lo,
    const ushort* __restrict__ P_hi, const ushort* __restrict__ Gt_hi,
    float* __restrict__ Yp,   // [KSPLIT][B][HW][32]
    float* __restrict__ Dp) { // [KSPLIT][B][HW]
  const int b     = blockIdx.z;
  const int ks    = blockIdx.y;
  const int q_blk = blockIdx.x;          // 0..99, 64 queries each
  const int tid   = threadIdx.x;
  const int w     = tid >> 6;            // wave 0..3 = key slice
  const int lane  = tid & 63;
  const int l15   = lane & 15;
  const int g     = lane >> 4;

  __shared__ float yl[4 * 32 * 33 + 4 * 32];   // epilogue only (17.2 KB)

  const int niter = 10;
  const int kbase = ks * 1280 + w * 32;  // this wave's first key

  // T fragments (theta*log2e, split) for q-subtiles s2 = 0..3
  bf16x8 t_hi[4], t_lo[4];
#pragma unroll
  for (int s2 = 0; s2 < 4; ++s2) {
    const int qrow = q_blk * 64 + s2 * 16 + l15;
    t_hi[s2] = *(const bf16x8*)&T_hi[b * PB + qrow * 32 + g * 8];
    t_lo[s2] = *(const bf16x8*)&T_lo[b * PB + qrow * 32 + g * 8];
  }

  // per-lane fragment sources
  const ushort* pg = P_hi + b * PB + (kbase + l15) * 32 + g * 8;
  const ushort* gg = Gt_hi + b * PB + l15 * HW + kbase + g * 8;

  f32x4 acc0[4] = {{0,0,0,0},{0,0,0,0},{0,0,0,0},{0,0,0,0}};  // chans 0..15
  f32x4 acc1[4] = {{0,0,0,0},{0,0,0,0},{0,0,0,0},{0,0,0,0}};  // chans 16..31
  float denom[4] = {0.f, 0.f, 0.f, 0.f};

  // pipeline stage 0
  bf16x8 pa = *(const bf16x8*)pg;
  bf16x8 pb = *(const bf16x8*)(pg + 512);        // +16 key rows
  bf16x8 g0 = *(const bf16x8*)gg;
  bf16x8 g1 = *(const bf16x8*)(gg + 16 * HW);    // +16 chan rows

  for (int i = 0; i < niter; ++i) {
    // issue next tile's loads (rotating register double-buffer)
    bf16x8 pan, pbn, g0n, g1n;
    if (i + 1 < niter) {
      const ushort* pgn = pg + (i + 1) * 4096;   // +128 keys * 32 chans
      const ushort* ggn = gg + (i + 1) * 128;    // +128 keys
      pan = *(const bf16x8*)pgn;
      pbn = *(const bf16x8*)(pgn + 512);
      g0n = *(const bf16x8*)ggn;
      g1n = *(const bf16x8*)(ggn + 16 * HW);
    }

#pragma unroll
    for (int s2 = 0; s2 < 4; ++s2) {
      f32x4 sa = {0.f,0.f,0.f,0.f};
      f32x4 sb = {0.f,0.f,0.f,0.f};
      __builtin_amdgcn_s_setprio(1);
      sa = MFMA16(pa, t_hi[s2], sa);
      sa = MFMA16(pa, t_lo[s2], sa);
      sb = MFMA16(pb, t_hi[s2], sb);
      sb = MFMA16(pb, t_lo[s2], sb);
      __builtin_amdgcn_s_setprio(0);

      const float ea0 = __builtin_amdgcn_exp2f(sa[0]);
      const float ea1 = __builtin_amdgcn_exp2f(sa[1]);
      const float ea2 = __builtin_amdgcn_exp2f(sa[2]);
      const float ea3 = __builtin_amdgcn_exp2f(sa[3]);
      const float eb0 = __builtin_amdgcn_exp2f(sb[0]);
      const float eb1 = __builtin_amdgcn_exp2f(sb[1]);
      const float eb2 = __builtin_amdgcn_exp2f(sb[2]);
      const float eb3 = __builtin_amdgcn_exp2f(sb[3]);
      denom[s2] += ((ea0 + ea1) + (ea2 + ea3)) + ((eb0 + eb1) + (eb2 + eb3));

      union { uint u[4]; bf16x8 v; } ph;
      ph.u[0] = pk2(ea0, ea1); ph.u[1] = pk2(ea2, ea3);
      ph.u[2] = pk2(eb0, eb1); ph.u[3] = pk2(eb2, eb3);

      __builtin_amdgcn_s_setprio(1);
      acc0[s2] = MFMA16(ph.v, g0, acc0[s2]);
      acc1[s2] = MFMA16(ph.v, g1, acc1[s2]);
      __builtin_amdgcn_s_setprio(0);
    }

    if (i + 1 < niter) { pa = pan; pb = pbn; g0 = g0n; g1 = g1n; }
  }

  // epilogue: combine the 4 key-slice waves via LDS, two passes of 32 queries
  float* dl = yl + 4 * 32 * 33;
  const int c  = tid & 31;
  const int q0 = tid >> 5;               // 0..7

#pragma unroll
  for (int p = 0; p < 2; ++p) {
    __syncthreads();                     // all waves ready / yl reusable
#pragma unroll
    for (int sl = 0; sl < 2; ++sl) {
      const int s2 = p * 2 + sl;
      float dn = denom[s2];
      dn += __shfl_xor(dn, 16);
      dn += __shfl_xor(dn, 32);
#pragma unroll
      for (int r = 0; r < 4; ++r) {
        yl[(w * 32 + sl * 16 + 4 * g + r) * 33 + l15]      = acc0[s2][r];
        yl[(w * 32 + sl * 16 + 4 * g + r) * 33 + 16 + l15] = acc1[s2][r];
      }
      if (g == 0) dl[w * 32 + sl * 16 + l15] = dn;
    }
    __syncthreads();

#pragma unroll
    for (int rr = 0; rr < 4; ++rr) {
      const int row = rr * 8 + q0;       // 0..31 within this pass
      float y = 0.f, d = 0.f;
#pragma unroll
      for (int k2 = 0; k2 < 4; ++k2) {
        y += yl[(k2 * 32 + row) * 33 + c];
        d += dl[k2 * 32 + row];
      }
      const int qrow = q_blk * 64 + p * 32 + row;
      Yp[((size_t)(ks * BATCH + b)) * PB + qrow * 32 + c] = y;
      if (c == 0) Dp[((size_t)(ks * BATCH + b)) * HW + qrow] = d;
    }
  }
}

// ---------------------------------------------------------------------------
// Kernel 3: final 1x1 conv fused with KSPLIT combine + normalize.
// grid (50, 2, B) x 128.
// ---------------------------------------------------------------------------
__global__ __launch_bounds__(128) void conv_out_kernel(
    const float* __restrict__ Yp, const float* __restrict__ Dp,
    const float* __restrict__ wy, const float* __restrict__ by,
    float* __restrict__ z) {
  const int b  = blockIdx.z;
  const int ih = blockIdx.y;            // i-half: 32 channels
  const int s  = blockIdx.x * 128 + threadIdx.x;

  __shared__ float wsm[32 * COUT];      // 4 KiB (this half's rows)
  for (int i = threadIdx.x; i < 32 * COUT; i += 128)
    wsm[i] = wy[ih * 32 * COUT + i];
  __syncthreads();

  float yr[COUT];
#pragma unroll
  for (int o = 0; o < COUT; ++o) {
    const int f = o * HW + s;
    const int n = f >> 5;
    float y = 0.f, d = 0.f;
#pragma unroll
    for (int ksi = 0; ksi < KSPLIT; ++ksi) {
      y += Yp[((size_t)(ksi * BATCH + b)) * PB + f];
      d += Dp[((size_t)(ksi * BATCH + b)) * HW + n];
    }
    yr[o] = y / d;
  }

  for (int ii = 0; ii < 32; ++ii) {
    const int i = ih * 32 + ii;
    const float4* wr = (const float4*)&wsm[ii * COUT];
    float acc = 0.f;
#pragma unroll
    for (int q = 0; q < COUT / 4; ++q) {
      float4 wv = wr[q];
      acc += wv.x * yr[4*q] + wv.y * yr[4*q+1] + wv.z * yr[4*q+2] + wv.w * yr[4*q+3];
    }
    z[(size_t)b * XB + i * HW + s] = acc + by[i];
  }
}

// ---------------------------------------------------------------------------
extern "C" void kernel_launch(void* const* d_in, const int* in_sizes, int n_in,
                              void* d_out, int out_size, void* d_ws, size_t ws_size,
                              hipStream_t stream) {
  const float* x       = (const float*)d_in[0];
  const float* w_g     = (const float*)d_in[1];
  const float* b_g     = (const float*)d_in[2];
  const float* w_phi   = (const float*)d_in[3];
  const float* b_phi   = (const float*)d_in[4];
  const float* w_theta = (const float*)d_in[5];
  const float* b_theta = (const float*)d_in[6];
  const float* w_y     = (const float*)d_in[7];
  const float* b_y     = (const float*)d_in[8];
  float* z = (float*)d_out;

  char* base = (char*)d_ws;
  const size_t BF = (size_t)BATCH * PB * sizeof(ushort);  // 819200 B
  ushort* T_hi  = (ushort*)(base);
  ushort* T_lo  = (ushort*)(base + 1 * BF);
  ushort* P_hi  = (ushort*)(base + 2 * BF);
  ushort* Gt_hi = (ushort*)(base + 3 * BF);
  float*  Yp    = (float*)(base + 4 * BF);                 // KSPLIT*B*PB f32
  float*  Dp    = (float*)(base + 4 * BF +
                           (size_t)KSPLIT * BATCH * PB * sizeof(float));

  conv3_kernel<<<dim3(50, 6, BATCH), 128, 0, stream>>>(
      x, w_theta, b_theta, w_phi, b_phi, w_g, b_g,
      T_hi, T_lo, P_hi, Gt_hi);
  attn_kernel<<<dim3(100, KSPLIT, BATCH), 256, 0, stream>>>(
      T_hi, T_lo, P_hi, Gt_hi, Yp, Dp);
  conv_out_kernel<<<dim3(50, 2, BATCH), 128, 0, stream>>>(Yp, Dp, w_y, b_y, z);
}